// Round 4
// baseline (43.104 us; speedup 1.0000x reference)
//
#include <hip/hip_runtime.h>
#include <math.h>

#define Hd 512
#define Bn 8
#define Sn 8192
#define SB 256            // energy blocks per b (32 rows each)

// ---------------------------------------------------------------------------
// K1: v[b,h] = sum_k hidden[b,k] * W[k,h].  grid Bn, block 512 (h = tid).
// W reads coalesced (thread h -> W[k*Hd+h]); hidden row is block-uniform.
// ---------------------------------------------------------------------------
__global__ __launch_bounds__(512) void k_proj(const float* __restrict__ hidden,
                                              const float* __restrict__ W,
                                              float* __restrict__ v) {
    const int b = blockIdx.x;
    const int h = threadIdx.x;
    float a0 = 0.f, a1 = 0.f, a2 = 0.f, a3 = 0.f;
    #pragma unroll 4
    for (int k = 0; k < Hd; k += 4) {
        const float4 hv = *(const float4*)(hidden + b * Hd + k);
        a0 += hv.x * W[(size_t)(k + 0) * Hd + h];
        a1 += hv.y * W[(size_t)(k + 1) * Hd + h];
        a2 += hv.z * W[(size_t)(k + 2) * Hd + h];
        a3 += hv.w * W[(size_t)(k + 3) * Hd + h];
    }
    v[b * Hd + h] = (a0 + a1) + (a2 + a3);
}

// ---------------------------------------------------------------------------
// K2: e[b,s] = enc[b,s,:] . v[b,:]  + per-block (max, sum-exp) partial.
// grid (SB, Bn), block 256 (4 waves); 8 rows per wave, packed 4-row reduce.
// ---------------------------------------------------------------------------
__global__ __launch_bounds__(256) void k_energy(const float* __restrict__ enc,
                                                const float* __restrict__ v,
                                                float* __restrict__ e,
                                                float2* __restrict__ partials) {
    const int sb   = blockIdx.x;
    const int b    = blockIdx.y;
    const int t    = threadIdx.x;
    const int wave = t >> 6, lane = t & 63;

    __shared__ float sm[32];

    const float4* vp = (const float4*)(v + b * Hd);
    const float4 v0 = vp[lane];
    const float4 v1 = vp[64 + lane];

    const int row0 = sb * 32 + wave * 8;
    const float4* base = (const float4*)(enc + ((size_t)b * Sn + row0) * Hd);

    #pragma unroll
    for (int rb = 0; rb < 8; rb += 4) {
        float p[4];
        #pragma unroll
        for (int r = 0; r < 4; ++r) {
            const float4* rowp = base + (size_t)(rb + r) * (Hd / 4);
            const float4 a0 = rowp[lane];
            const float4 a1 = rowp[64 + lane];
            p[r] = a0.x * v0.x + a0.y * v0.y + a0.z * v0.z + a0.w * v0.w
                 + a1.x * v1.x + a1.y * v1.y + a1.z * v1.z + a1.w * v1.w;
        }
        // packed reduce: after this, lane l (l<4) holds full sum of row rb+l
        float s0 = p[0] + __shfl_xor(p[0], 1, 64);
        float s1 = p[1] + __shfl_xor(p[1], 1, 64);
        float s2 = p[2] + __shfl_xor(p[2], 1, 64);
        float s3 = p[3] + __shfl_xor(p[3], 1, 64);
        float t0 = (lane & 1) ? s1 : s0;
        float t1 = (lane & 1) ? s3 : s2;
        t0 += __shfl_xor(t0, 2, 64);
        t1 += __shfl_xor(t1, 2, 64);
        float w = (lane & 2) ? t1 : t0;
        w += __shfl_xor(w, 4, 64);
        w += __shfl_xor(w, 8, 64);
        w += __shfl_xor(w, 16, 64);
        w += __shfl_xor(w, 32, 64);
        if (lane < 4) sm[wave * 8 + rb + lane] = w;
    }
    __syncthreads();

    // wave 0: write e + per-block (m, l) partial
    if (wave == 0) {
        const float ev = (lane < 32) ? sm[lane] : -INFINITY;
        float m = ev;
        #pragma unroll
        for (int off = 32; off >= 1; off >>= 1)
            m = fmaxf(m, __shfl_xor(m, off, 64));
        float l = (lane < 32) ? __expf(ev - m) : 0.f;
        #pragma unroll
        for (int off = 32; off >= 1; off >>= 1)
            l += __shfl_xor(l, off, 64);
        if (lane < 32) e[(size_t)b * Sn + sb * 32 + lane] = ev;
        if (lane == 0) partials[b * SB + sb] = make_float2(m, l);
    }
}

// ---------------------------------------------------------------------------
// K3: out[b,j] = exp(e[b,j] - M_b) / L_b.  grid (16, Bn), block 512.
// Each wave redundantly LSE-merges the 256 partials of its b in-register.
// ---------------------------------------------------------------------------
__global__ __launch_bounds__(512) void k_finalize(const float* __restrict__ e,
                                                  const float2* __restrict__ partials,
                                                  float* __restrict__ out) {
    const int b    = blockIdx.y;
    const int t    = threadIdx.x;
    const int lane = t & 63;

    const float2* pp = partials + b * SB;
    float2 p0 = pp[lane];
    float M = p0.x, L = p0.y;
    #pragma unroll
    for (int i = 1; i < 4; ++i) {
        const float2 pi = pp[lane + 64 * i];
        const float Mn = fmaxf(M, pi.x);
        L = L * __expf(M - Mn) + pi.y * __expf(pi.x - Mn);
        M = Mn;
    }
    #pragma unroll
    for (int off = 32; off >= 1; off >>= 1) {
        const float Mo = __shfl_xor(M, off, 64);
        const float Lo = __shfl_xor(L, off, 64);
        const float Mn = fmaxf(M, Mo);
        L = L * __expf(M - Mn) + Lo * __expf(Mo - Mn);
        M = Mn;
    }
    const float inv = 1.0f / L;

    const size_t j = (size_t)b * Sn + blockIdx.x * 512 + t;
    out[j] = __expf(e[j] - M) * inv;
}

// ---------------------------------------------------------------------------
extern "C" void kernel_launch(void* const* d_in, const int* in_sizes, int n_in,
                              void* d_out, int out_size, void* d_ws, size_t ws_size,
                              hipStream_t stream) {
    const float* hidden = (const float*)d_in[0];   // [1,B,H]
    const float* enc    = (const float*)d_in[1];   // [B,S,H]
    const float* W      = (const float*)d_in[2];   // [H,H]
    // d_in[3] (bias) unused: softmax over s is shift-invariant; bias adds a
    // per-b constant c[b] = bias . h[b] that cancels.
    float* out = (float*)d_out;                    // [B,S] f32

    float*  v        = (float*)d_ws;               // Bn*Hd floats (16 KB)
    float2* partials = (float2*)(v + Bn * Hd);     // Bn*SB float2 (16 KB)
    float*  e        = (float*)(partials + Bn * SB); // Bn*Sn floats (256 KB)

    k_proj    <<<Bn,              512, 0, stream>>>(hidden, W, v);
    k_energy  <<<dim3(SB, Bn),    256, 0, stream>>>(enc, v, e, partials);
    k_finalize<<<dim3(16, Bn),    512, 0, stream>>>(e, partials, out);
}

// Round 5
// 32.549 us; speedup vs baseline: 1.3243x; 1.3243x over previous
//
#include <hip/hip_runtime.h>
#include <math.h>

#define Hd 512
#define Bn 8
#define Sn 8192
#define SB 256            // energy blocks per b (32 rows each)

// ---------------------------------------------------------------------------
// K1: v[b,h] = sum_k hidden[b,k] * W[k,h], partitioned by h-columns.
// grid (16, Bn): block (hc,b) computes v[b, hc*32 .. hc*32+31] fully summed.
// block 256 = 8 k-groups x 32 cols; LDS 8x32 reduce. No atomics, no slabs.
// ---------------------------------------------------------------------------
__global__ __launch_bounds__(256) void k_proj(const float* __restrict__ hidden,
                                              const float* __restrict__ W,
                                              float* __restrict__ v) {
    const int hc = blockIdx.x;        // 0..15
    const int b  = blockIdx.y;
    const int t  = threadIdx.x;
    const int kg = t >> 5;            // 0..7  (k-group: 64 k's each)
    const int c  = t & 31;            // 0..31 (column within stripe)
    const int col = hc * 32 + c;

    __shared__ float hs[Hd];
    __shared__ float partial[8][32];

    hs[t]       = hidden[b * Hd + t];
    hs[t + 256] = hidden[b * Hd + t + 256];
    __syncthreads();

    float acc = 0.f;
    const int k0 = kg * 64;
    #pragma unroll 8
    for (int i = 0; i < 64; ++i)
        acc += hs[k0 + i] * W[(size_t)(k0 + i) * Hd + col];
    partial[kg][c] = acc;
    __syncthreads();

    if (t < 32) {
        float s = partial[0][t];
        #pragma unroll
        for (int j = 1; j < 8; ++j) s += partial[j][t];
        v[b * Hd + hc * 32 + t] = s;
    }
}

// ---------------------------------------------------------------------------
// K2: e[b,s] = enc[b,s,:] . v[b,:]  + per-block (max, sum-exp) partial.
// grid (SB, Bn), block 256 (4 waves); 8 rows per wave, packed 4-row reduce.
// ---------------------------------------------------------------------------
__global__ __launch_bounds__(256) void k_energy(const float* __restrict__ enc,
                                                const float* __restrict__ v,
                                                float* __restrict__ e,
                                                float2* __restrict__ partials) {
    const int sb   = blockIdx.x;
    const int b    = blockIdx.y;
    const int t    = threadIdx.x;
    const int wave = t >> 6, lane = t & 63;

    __shared__ float sm[32];

    const float4* vp = (const float4*)(v + b * Hd);
    const float4 v0 = vp[lane];
    const float4 v1 = vp[64 + lane];

    const int row0 = sb * 32 + wave * 8;
    const float4* base = (const float4*)(enc + ((size_t)b * Sn + row0) * Hd);

    #pragma unroll
    for (int rb = 0; rb < 8; rb += 4) {
        float p[4];
        #pragma unroll
        for (int r = 0; r < 4; ++r) {
            const float4* rowp = base + (size_t)(rb + r) * (Hd / 4);
            const float4 a0 = rowp[lane];
            const float4 a1 = rowp[64 + lane];
            p[r] = a0.x * v0.x + a0.y * v0.y + a0.z * v0.z + a0.w * v0.w
                 + a1.x * v1.x + a1.y * v1.y + a1.z * v1.z + a1.w * v1.w;
        }
        // packed reduce: after this, lane l (l<4) holds full sum of row rb+l
        float s0 = p[0] + __shfl_xor(p[0], 1, 64);
        float s1 = p[1] + __shfl_xor(p[1], 1, 64);
        float s2 = p[2] + __shfl_xor(p[2], 1, 64);
        float s3 = p[3] + __shfl_xor(p[3], 1, 64);
        float t0 = (lane & 1) ? s1 : s0;
        float t1 = (lane & 1) ? s3 : s2;
        t0 += __shfl_xor(t0, 2, 64);
        t1 += __shfl_xor(t1, 2, 64);
        float w = (lane & 2) ? t1 : t0;
        w += __shfl_xor(w, 4, 64);
        w += __shfl_xor(w, 8, 64);
        w += __shfl_xor(w, 16, 64);
        w += __shfl_xor(w, 32, 64);
        if (lane < 4) sm[wave * 8 + rb + lane] = w;
    }
    __syncthreads();

    // wave 0: write e + per-block (m, l) partial
    if (wave == 0) {
        const float ev = (lane < 32) ? sm[lane] : -INFINITY;
        float m = ev;
        #pragma unroll
        for (int off = 32; off >= 1; off >>= 1)
            m = fmaxf(m, __shfl_xor(m, off, 64));
        float l = (lane < 32) ? __expf(ev - m) : 0.f;
        #pragma unroll
        for (int off = 32; off >= 1; off >>= 1)
            l += __shfl_xor(l, off, 64);
        if (lane < 32) e[(size_t)b * Sn + sb * 32 + lane] = ev;
        if (lane == 0) partials[b * SB + sb] = make_float2(m, l);
    }
}

// ---------------------------------------------------------------------------
// K3: out[b,j] = exp(e[b,j] - M_b) / L_b.  grid (16, Bn), block 512.
// Each wave redundantly LSE-merges the 256 partials of its b in-register.
// ---------------------------------------------------------------------------
__global__ __launch_bounds__(512) void k_finalize(const float* __restrict__ e,
                                                  const float2* __restrict__ partials,
                                                  float* __restrict__ out) {
    const int b    = blockIdx.y;
    const int t    = threadIdx.x;
    const int lane = t & 63;

    const float2* pp = partials + b * SB;
    float2 p0 = pp[lane];
    float M = p0.x, L = p0.y;
    #pragma unroll
    for (int i = 1; i < 4; ++i) {
        const float2 pi = pp[lane + 64 * i];
        const float Mn = fmaxf(M, pi.x);
        L = L * __expf(M - Mn) + pi.y * __expf(pi.x - Mn);
        M = Mn;
    }
    #pragma unroll
    for (int off = 32; off >= 1; off >>= 1) {
        const float Mo = __shfl_xor(M, off, 64);
        const float Lo = __shfl_xor(L, off, 64);
        const float Mn = fmaxf(M, Mo);
        L = L * __expf(M - Mn) + Lo * __expf(Mo - Mn);
        M = Mn;
    }
    const float inv = 1.0f / L;

    const size_t j = (size_t)b * Sn + blockIdx.x * 512 + t;
    out[j] = __expf(e[j] - M) * inv;
}

// ---------------------------------------------------------------------------
extern "C" void kernel_launch(void* const* d_in, const int* in_sizes, int n_in,
                              void* d_out, int out_size, void* d_ws, size_t ws_size,
                              hipStream_t stream) {
    const float* hidden = (const float*)d_in[0];   // [1,B,H]
    const float* enc    = (const float*)d_in[1];   // [B,S,H]
    const float* W      = (const float*)d_in[2];   // [H,H]
    // d_in[3] (bias) unused: softmax over s is shift-invariant; bias adds a
    // per-b constant c[b] = bias . h[b] that cancels.
    float* out = (float*)d_out;                    // [B,S] f32

    float*  v        = (float*)d_ws;               // Bn*Hd floats (16 KB)
    float2* partials = (float2*)(v + Bn * Hd);     // Bn*SB float2 (16 KB)
    float*  e        = (float*)(partials + Bn * SB); // Bn*Sn floats (256 KB)

    k_proj    <<<dim3(16, Bn), 256, 0, stream>>>(hidden, W, v);
    k_energy  <<<dim3(SB, Bn), 256, 0, stream>>>(enc, v, e, partials);
    k_finalize<<<dim3(16, Bn), 512, 0, stream>>>(e, partials, out);
}